// Round 3
// baseline (158.135 us; speedup 1.0000x reference)
//
#include <hip/hip_runtime.h>
#include <hip/hip_bf16.h>
#include <math.h>

typedef _Float16 half8 __attribute__((ext_vector_type(8)));
typedef float f32x4 __attribute__((ext_vector_type(4)));

#define BATCH 100
#define CH    512
#define HWP   256
#define SAMP  (CH * HWP)   // 131072 elems per sample

// Packed fragment layout (both operands, K-contiguous rows):
//   tile (row_tile = row>>4, k_tile = c>>5) of 1 KB = 64 lanes x 16 B
//   lane = (row&15) + (((c>>3)&3)<<4), slot = c&7
//   off_halfs = (row_tile*NKT + k_tile)*512 + lane*8      (NKT = 16 k-tiles)
// This IS the mfma_f32_16x16x32_f16 A/B fragment order: one wave-load of a
// tile (addr = base + lane*16B, fully coalesced) yields af/bf directly.

// ---- async global->LDS 16B (wave-uniform LDS base + lane*16) ----
__device__ __forceinline__ void async16(const void* g, void* l) {
  __builtin_amdgcn_global_load_lds(
      (const __attribute__((address_space(1))) unsigned int*)g,
      (__attribute__((address_space(3))) unsigned int*)l, 16, 0, 0);
}

// ---- K0: transpose + fp32->fp16 + fragment-pack:  x[b][c][p] -> xhp packed
// 64c x 64p tile per block; LDS fp32 [64][69] (pad 5 -> max 2-way alias = free).
// Blocks >= 3200: W fp32->fp16 fragment-pack (128 blocks).
__global__ __launch_bounds__(256) void k_txpose(const float* __restrict__ x,
                                               _Float16* __restrict__ xhp,
                                               const float* __restrict__ W,
                                               _Float16* __restrict__ Whp) {
  __shared__ float tb[64][69];
  int bid  = blockIdx.x;
  if (bid >= 3200) {                 // W pack tail: 128 blocks, 1 chunk/thread
    int tid = (bid - 3200) * 256 + threadIdx.x;   // 0..32767
    int o  = tid >> 6, c8 = tid & 63;
    const float* wp = W + (size_t)o * 512 + c8 * 8;
    half8 h;
#pragma unroll
    for (int j = 0; j < 8; j++) h[j] = (_Float16)wp[j];
    *(half8*)(Whp + (size_t)((o >> 4) * 16 + (c8 >> 2)) * 512
              + ((o & 15) + ((c8 & 3) << 4)) * 8) = h;
    return;
  }
  int b    = bid >> 5;          // 32 tiles per batch
  int tile = bid & 31;
  int c0 = (tile >> 2) << 6;    // 8 c-tiles of 64
  int p0 = (tile & 3) << 6;     // 4 p-tiles of 64
  int t = threadIdx.x;
  const float* xb = x + (size_t)b * SAMP;
#pragma unroll
  for (int it = 0; it < 4; it++) {
    int ch = it * 256 + t;
    int c  = ch >> 4;           // 0..63
    int pc = (ch & 15) << 2;    // 0..60
    float4 v = *(const float4*)(xb + (size_t)(c0 + c) * HWP + p0 + pc);
    tb[c][pc] = v.x; tb[c][pc + 1] = v.y; tb[c][pc + 2] = v.z; tb[c][pc + 3] = v.w;
  }
  __syncthreads();
  _Float16* xhb = xhp + (size_t)b * SAMP;
#pragma unroll
  for (int it = 0; it < 2; it++) {
    int ch = it * 256 + t;
    int p  = ch >> 3;           // 0..63 local p
    int c8 = ch & 7;            // local c-octet
    half8 h;
#pragma unroll
    for (int j = 0; j < 8; j++) h[j] = (_Float16)tb[c8 * 8 + j][p];
    int pg  = p0 + p;
    int c8g = (c0 >> 3) + c8;
    *(half8*)(xhb + (size_t)((pg >> 4) * 16 + (c8g >> 2)) * 512
              + ((pg & 15) + ((c8g & 3) << 4)) * 8) = h;
  }
}

// ---- K1: batched GEMM + fused exp + denom partial + u = x*e (fp16) store.
// LDS-FREE, BARRIER-FREE K-loop: operands are pre-packed in fragment order, so
// each af[i]/bf[j] is ONE coalesced global_load_dwordx4 (lane-linear 1-KB tile).
// 2-deep register pipeline; compiler emits counted vmcnt (no barrier -> no
// vmcnt(0) drain). Waves are fully independent -> latency hides via TLP.
// Epilogue x-tile is DMA'd (global_load_lds) BEFORE the K-loop: linear LDS dest,
// XOR-pre-swizzled source chunks, matching swizzled read (rule-21 pattern).
__global__ __launch_bounds__(256) void k_gemm(const _Float16* __restrict__ Whp,
                                             const _Float16* __restrict__ xhp,
                                             const float* __restrict__ bias,
                                             _Float16* __restrict__ u,
                                             float* __restrict__ denom) {
  __shared__ __align__(16) _Float16 smem[128 * 128];   // 32 KiB epilogue x-tile
  __shared__ float rs[4];
  int bid = blockIdx.x;
  // bijective XCD swizzle (800 % 8 == 0): 8 subtiles of a batch share one XCD L2
  int w     = (bid & 7) * 100 + (bid >> 3);
  int batch = w >> 3;
  int sub   = w & 7;
  int ot = sub & 3, pt = sub >> 2;
  int o0 = ot * 128, p0 = pt * 128;
  const _Float16* Xb = xhp + (size_t)batch * SAMP;

  int t  = threadIdx.x;
  int wv = t >> 6, ln = t & 63;
  int qd = ln >> 4, r = ln & 15;
  int wm0 = (wv >> 1) * 64, wn0 = (wv & 1) * 64;

  // fragment bases (include lane offset); frag (i,ks) at + (i*16+ks)*512
  const _Float16* Ab = Whp + (size_t)((o0 + wm0) >> 4) * 16 * 512 + ln * 8;
  const _Float16* Bb = Xb  + (size_t)((p0 + wn0) >> 4) * 16 * 512 + ln * 8;

#define LOADF(aa, bb, ks)                                                     \
  { _Pragma("unroll")                                                         \
    for (int i = 0; i < 4; i++)                                               \
      aa[i] = *(const half8*)(Ab + (size_t)(i * 16 + (ks)) * 512);            \
    _Pragma("unroll")                                                         \
    for (int j = 0; j < 4; j++)                                               \
      bb[j] = *(const half8*)(Bb + (size_t)(j * 16 + (ks)) * 512); }

#define MFMA16(aa, bb)                                                        \
  { _Pragma("unroll")                                                         \
    for (int i = 0; i < 4; i++)                                               \
      _Pragma("unroll")                                                       \
      for (int j = 0; j < 4; j++)                                             \
        acc[i][j] = __builtin_amdgcn_mfma_f32_16x16x32_f16(aa[i], bb[j], acc[i][j], 0, 0, 0); }

  f32x4 acc[4][4] = {};
  half8 a0[4], b0[4], a1[4], b1[4];
  LOADF(a0, b0, 0);

  // issue epilogue x-tile DMA now; it completes during the K-loop.
  // LDS slot s = p*16 + lc8 (linear); source chunk octet = lc8 ^ (p&7).
#pragma unroll
  for (int it = 0; it < 8; it++) {
    int s   = it * 256 + t;
    int p   = s >> 4, lc8 = s & 15;
    int pg  = p0 + p;
    int c8g = (o0 >> 3) + (lc8 ^ (p & 7));
    const _Float16* src = Xb + (size_t)((pg >> 4) * 16 + (c8g >> 2)) * 512
                             + ((pg & 15) + ((c8g & 3) << 4)) * 8;
    async16(src, smem + (size_t)(it * 256 + wv * 64) * 8);
  }

#pragma unroll
  for (int ks = 0; ks < 16; ks += 2) {
    LOADF(a1, b1, ks + 1);
    MFMA16(a0, b0);
    if (ks < 14) LOADF(a0, b0, ks + 2);
    MFMA16(a1, b1);
  }
#undef LOADF
#undef MFMA16

  __syncthreads();   // single barrier: drains DMA, LDS x-tile ready

  _Float16* outb = u + (size_t)batch * SAMP;    // [o][p]
  float lsum = 0.f;
#pragma unroll
  for (int i = 0; i < 4; i++) {
#pragma unroll
    for (int rg = 0; rg < 4; rg++) {
      int ol = wm0 + i * 16 + qd * 4 + rg;      // local o (== mask channel)
      float bv = bias[o0 + ol];
      int lo = ol >> 3, wo = ol & 7;
#pragma unroll
      for (int j = 0; j < 4; j++) {
        int pl = wn0 + j * 16 + r;              // local p
        float ev = __expf(acc[i][j][rg] + bv);
        lsum += ev;
        float xv = (float)smem[pl * 128 + ((lo ^ (pl & 7)) << 3) + wo];
        outb[(size_t)(o0 + ol) * HWP + p0 + pl] = (_Float16)(xv * ev);
      }
    }
  }
#pragma unroll
  for (int off = 32; off; off >>= 1) lsum += __shfl_down(lsum, off, 64);
  if (ln == 0) rs[wv] = lsum;
  __syncthreads();
  if (t == 0) atomicAdd(&denom[batch], rs[0] + rs[1] + rs[2] + rs[3]);
}

// ---- K3: prototypes s[m][c] = (1/1280) * sum_j invd_j * sum_p u ----
// One block per channel c; 5 prototypes each.
__global__ __launch_bounds__(256) void k_proto(const _Float16* __restrict__ u,
                                              const float* __restrict__ denom,
                                              float* __restrict__ sproto) {
  int c = blockIdx.x;
  int t = threadIdx.x;                 // position p
  int wv = t >> 6;
  float accm[5];
#pragma unroll
  for (int m = 0; m < 5; m++) {
    float acc = 0.f;
#pragma unroll
    for (int j = 0; j < 5; j++) {
      int b = m * 20 + j;
      acc += (float)u[(size_t)b * SAMP + (size_t)c * HWP + t] * (1.0f / denom[b]);
    }
    accm[m] = acc;
  }
#pragma unroll
  for (int m = 0; m < 5; m++) {
    float v = accm[m];
#pragma unroll
    for (int off = 32; off; off >>= 1) v += __shfl_down(v, off, 64);
    accm[m] = v;
  }
  __shared__ float rs[4][5];
  if ((t & 63) == 0) {
#pragma unroll
    for (int m = 0; m < 5; m++) rs[wv][m] = accm[m];
  }
  __syncthreads();
  if (t < 5) sproto[t * 512 + c] =
      (rs[0][t] + rs[1][t] + rs[2][t] + rs[3][t]) * (1.0f / 1280.0f);
}

// ---- K3b: pref[m] = SCALE / max(||s[m]||, eps) ----
__global__ __launch_bounds__(256) void k_sn(const float* __restrict__ sproto,
                                           float* __restrict__ pref) {
  int m = blockIdx.x, t = threadIdx.x;
  float v1 = sproto[m * 512 + t], v2 = sproto[m * 512 + 256 + t];
  float acc = v1 * v1 + v2 * v2;
#pragma unroll
  for (int off = 32; off; off >>= 1) acc += __shfl_down(acc, off, 64);
  __shared__ float rs[4];
  if ((t & 63) == 0) rs[t >> 6] = acc;
  __syncthreads();
  if (t == 0) {
    float sn = fmaxf(sqrtf(rs[0] + rs[1] + rs[2] + rs[3]), 1e-8f);
    pref[m] = 10.0f / sn;
  }
}

// ---- K4a: per (query n, c-chunk gc of 64): partial dots + qq from u (fp16) ----
// part layout [n][gc][6][256] -> fully coalesced stores/loads.
__global__ __launch_bounds__(256) void k_part(const _Float16* __restrict__ u,
                                             const float* __restrict__ sproto,
                                             float* __restrict__ part) {
  __shared__ float s_l[5 * 64];
  int n = blockIdx.x >> 3, gc = blockIdx.x & 7;
  int b = (n / 15) * 20 + 5 + (n % 15);
  int t = threadIdx.x;                // position f
  for (int i = t; i < 320; i += 256)  // 320 entries > 256 threads
    s_l[i] = sproto[(i >> 6) * 512 + gc * 64 + (i & 63)];
  __syncthreads();
  const _Float16* ub = u + (size_t)b * SAMP + (size_t)gc * 64 * HWP;
  float dot[5] = {0, 0, 0, 0, 0}, qq = 0.f;
#pragma unroll 8
  for (int c = 0; c < 64; c++) {
    float v = (float)ub[c * HWP + t];
    qq += v * v;
#pragma unroll
    for (int m = 0; m < 5; m++) dot[m] += v * s_l[m * 64 + c];
  }
  float* pp = part + (size_t)(n * 8 + gc) * 6 * 256 + t;
  pp[0 * 256] = dot[0]; pp[1 * 256] = dot[1]; pp[2 * 256] = dot[2];
  pp[3 * 256] = dot[3]; pp[4 * 256] = dot[4]; pp[5 * 256] = qq;
}

// ---- K4b: combine partials -> cosine -> softmax(5) -> spatial mean ----
__global__ __launch_bounds__(256) void k_comb(const float* __restrict__ part,
                                             const float* __restrict__ pref,
                                             float* __restrict__ out) {
  int n = blockIdx.x, t = threadIdx.x;   // t = position f
  float dot[5] = {0, 0, 0, 0, 0}, qq = 0.f;
#pragma unroll
  for (int gc = 0; gc < 8; gc++) {
    const float* pp = part + (size_t)(n * 8 + gc) * 6 * 256 + t;
    dot[0] += pp[0 * 256]; dot[1] += pp[1 * 256]; dot[2] += pp[2 * 256];
    dot[3] += pp[3 * 256]; dot[4] += pp[4 * 256]; qq += pp[5 * 256];
  }
  float iqn = 1.0f / fmaxf(sqrtf(qq), 1e-20f);
  float sc[5], mx = -1e30f;
#pragma unroll
  for (int m = 0; m < 5; m++) { sc[m] = dot[m] * pref[m] * iqn; mx = fmaxf(mx, sc[m]); }
  float p[5], ssum = 0.f;
#pragma unroll
  for (int m = 0; m < 5; m++) { p[m] = __expf(sc[m] - mx); ssum += p[m]; }
  float rr = 1.0f / ssum;
#pragma unroll
  for (int m = 0; m < 5; m++) {
    float v = p[m] * rr;
#pragma unroll
    for (int off = 32; off; off >>= 1) v += __shfl_down(v, off, 64);
    p[m] = v;   // lane0 of each wave holds wave sum
  }
  __shared__ float rs[4][5];
  if ((t & 63) == 0) {
#pragma unroll
    for (int m = 0; m < 5; m++) rs[t >> 6][m] = p[m];
  }
  __syncthreads();
  if (t < 5) out[n * 5 + t] =
      (rs[0][t] + rs[1][t] + rs[2][t] + rs[3][t]) * (1.0f / 256.0f);
}

extern "C" void kernel_launch(void* const* d_in, const int* in_sizes, int n_in,
                              void* d_out, int out_size, void* d_ws, size_t ws_size,
                              hipStream_t stream) {
  const float* x    = (const float*)d_in[0];   // (100,512,16,16)
  const float* W    = (const float*)d_in[1];   // (512,512)
  const float* bias = (const float*)d_in[2];   // (512,)
  float* out = (float*)d_out;                  // (75,5) fp32

  char* ws = (char*)d_ws;
  _Float16* xhp    = (_Float16*)(ws + 0);          // 26,214,400 B (dead after gemm)
  float*    part   = (float*)   (ws + 0);          //  2,764,800 B (aliases xhp)
  _Float16* Whp    = (_Float16*)(ws + 26214400);   //    524,288 B
  _Float16* u      = (_Float16*)(ws + 26738688);   // 26,214,400 B  u = x*exp(logit)
  float*    denom  = (float*)   (ws + 52953088);   //        512 B
  float*    sproto = (float*)   (ws + 52953600);   //     10,240 B
  float*    pref   = (float*)   (ws + 52963840);   //        512 B

  hipMemsetAsync(denom, 0, 512, stream);
  k_txpose <<<3328, 256, 0, stream>>>(x, xhp, W, Whp);  // 3200 pack + 128 W-pack
  k_gemm   <<<800,  256, 0, stream>>>(Whp, xhp, bias, u, denom);
  k_proto  <<<512,  256, 0, stream>>>(u, denom, sproto);
  k_sn     <<<5,    256, 0, stream>>>(sproto, pref);
  k_part   <<<600,  256, 0, stream>>>(u, sproto, part);
  k_comb   <<<75,   256, 0, stream>>>(part, pref, out);
}